// Round 1
// baseline (5881.351 us; speedup 1.0000x reference)
//
#include <hip/hip_runtime.h>
#include <stdint.h>

#define Bsz 1024
#define Hsz 1024
#define Psteps 96
#define Ssamp 100
#define COVn 31

typedef __attribute__((ext_vector_type(8))) short short8;
typedef __attribute__((ext_vector_type(4))) float f32x4;

__device__ inline unsigned short f2bf(float f) {
    union { float f; unsigned u; } v; v.f = f;
    unsigned r = v.u + 0x7FFFu + ((v.u >> 16) & 1u);
    return (unsigned short)(r >> 16);
}

__device__ inline float sigm(float x) { return 1.f / (1.f + __expf(-x)); }
__device__ inline float tanh_f(float x) { return 2.f / (1.f + __expf(-2.f * x)) - 1.f; }
__device__ inline float softplusf(float x) {
    return fmaxf(x, 0.f) + log1pf(__expf(-fabsf(x)));
}

__device__ inline void gld16(const unsigned short* g, unsigned short* l) {
    auto gp = (const __attribute__((address_space(1))) unsigned int*)(const unsigned int*)g;
    auto lp = (__attribute__((address_space(3))) unsigned int*)(unsigned int*)l;
    __builtin_amdgcn_global_load_lds(gp, lp, 16, 0, 0);
}

// ---------------- prep kernels ----------------
__global__ void prep_weights(const float* __restrict__ Wih0, const float* __restrict__ Whh0,
                             const float* __restrict__ Wih1, const float* __restrict__ Whh1,
                             const float* __restrict__ bih0, const float* __restrict__ bhh0,
                             const float* __restrict__ bih1, const float* __restrict__ bhh1,
                             unsigned short* __restrict__ Wih0h, unsigned short* __restrict__ Whh0h,
                             unsigned short* __restrict__ Wih1h, unsigned short* __restrict__ Whh1h,
                             float* __restrict__ bias0, float* __restrict__ bias1) {
    const size_t NB = (size_t)4096 * 1024;
    const size_t total = 3 * NB + 4096 * 32 + 8192;
    for (size_t e = (size_t)blockIdx.x * 256 + threadIdx.x; e < total; e += (size_t)gridDim.x * 256) {
        if (e < 3 * NB) {
            size_t m = e % NB;
            int which = (int)(e / NB);
            int gh = (int)(m >> 10), k = (int)(m & 1023);
            int src = ((gh & 3) << 10) + (gh >> 2);   // W_hat[4h+g] = W[g*H+h]
            const float* W = which == 0 ? Whh0 : which == 1 ? Wih1 : Whh1;
            unsigned short* D = which == 0 ? Whh0h : which == 1 ? Wih1h : Whh1h;
            D[m] = f2bf(W[(size_t)src * 1024 + k]);
        } else if (e < 3 * NB + 4096 * 32) {
            size_t m = e - 3 * NB;
            int gh = (int)(m >> 5), k = (int)(m & 31);
            int src = ((gh & 3) << 10) + (gh >> 2);
            Wih0h[m] = f2bf(Wih0[(size_t)src * 32 + k]);
        } else {
            size_t m = e - 3 * NB - 4096 * 32;  // 0..8191
            int which = (int)(m >> 12);
            int gh = (int)(m & 4095);
            int src = ((gh & 3) << 10) + (gh >> 2);
            if (which == 0) bias0[gh] = bih0[src] + bhh0[src];
            else            bias1[gh] = bih1[src] + bhh1[src];
        }
    }
}

__global__ void prep_state(const float* __restrict__ hinit, const float* __restrict__ cinit,
                           unsigned short* __restrict__ hb0, unsigned short* __restrict__ hb1,
                           float* __restrict__ c0, float* __restrict__ c1) {
    const size_t NM = (size_t)1024 * 1024;
    for (size_t e = (size_t)blockIdx.x * 256 + threadIdx.x; e < 4 * NM; e += (size_t)gridDim.x * 256) {
        if (e < NM) {
            hb0[e] = f2bf(hinit[e]);
        } else if (e < 2 * NM) {
            hb1[e - NM] = f2bf(hinit[e]);
        } else if (e < 3 * NM) {
            size_t j = e - 2 * NM; int h = (int)(j >> 10), b = (int)(j & 1023);
            c0[j] = cinit[(size_t)b * 1024 + h];          // c stored [H][B]
        } else {
            size_t j = e - 3 * NM; int h = (int)(j >> 10), b = (int)(j & 1023);
            c1[j] = cinit[NM + (size_t)b * 1024 + h];
        }
    }
}

// ---------------- LSTM step GEMM kernel ----------------
// gates^T = W_hat (M=4096, interleaved ĝ=4h+g) x input^T (N=1024 batch)
// block tile: 128 gate rows x 64 batch cols; 4 waves as 2(M)x2(N); wave = 64x32
template<int CELL>
__global__ __launch_bounds__(256, 2) void lstm_step(
        int t,
        const float* __restrict__ cov, const float* __restrict__ initv,
        const float* __restrict__ noise, const float* __restrict__ bproj,
        const float* __restrict__ wproj,
        const unsigned short* __restrict__ WihH, const unsigned short* __restrict__ WhhH,
        const float* __restrict__ biasH,
        const unsigned short* __restrict__ hA,   // cell1: h0_new (B-src for Wih1)
        const unsigned short* __restrict__ hB,   // cell0: h0_prev; cell1: h1_prev
        unsigned short* __restrict__ hOut,
        float* __restrict__ cws,
        const float* __restrict__ pbufPrev, float* __restrict__ pbufCur,
        float* __restrict__ outParams) {
    __shared__ __align__(16) unsigned short Ab[128 * 32];
    __shared__ __align__(16) unsigned short Bb[64 * 32];
    __shared__ __align__(16) unsigned short Xb[64 * 32];
    __shared__ float curL[64];

    const int tid = threadIdx.x;
    const int m_tile = blockIdx.x & 31;
    const int n_tile = blockIdx.x >> 5;
    const int m0 = m_tile * 128;          // gate-row (ĝ) base
    const int hc0 = m_tile * 32;          // h-col base
    const int b0 = n_tile * 64;
    const int lane = tid & 63;
    const int wid = tid >> 6;
    const int wm = wid >> 1, wn = wid & 1;

    if (CELL == 0) {
        if (m_tile == 0 && tid < 128) {
            pbufCur[b0 * 2 + tid] = 0.f;   // zero accumulation target for this step
            if (t > 0) {
                int b = b0 + (tid >> 1), j = tid & 1;
                outParams[((size_t)b * Psteps + (t - 1)) * 2 + j] = pbufPrev[b * 2 + j] + bproj[j];
            }
        }
        if (tid < 64) {
            int b = b0 + tid;
            float cu;
            if (t == 0) {
                cu = initv[b];
            } else {
                float p0 = pbufPrev[b * 2 + 0] + bproj[0];
                float p1 = pbufPrev[b * 2 + 1] + bproj[1];
                float sg = softplusf(p1) + 1e-6f;
                cu = p0 + sg * noise[(size_t)(t - 1) * Ssamp * Bsz + b];
            }
            curL[tid] = cu;
        }
        __syncthreads();
        {   // build x tile [64 rows][32 cols] bf16: col0=cur, col 1..31 = cov[b][t][0..30]
            int r = tid >> 2;
            int c8 = (tid & 3) * 8;
            const float* cr = cov + ((size_t)(b0 + r) * Psteps + t) * COVn;
            #pragma unroll
            for (int e = 0; e < 8; ++e) {
                int col = c8 + e;
                float v = (col == 0) ? curL[r] : cr[col - 1];
                Xb[r * 32 + col] = f2bf(v);
            }
        }
    }

    f32x4 acc[4][2];
    #pragma unroll
    for (int i = 0; i < 4; ++i)
        #pragma unroll
        for (int j = 0; j < 2; ++j) acc[i][j] = (f32x4){0.f, 0.f, 0.f, 0.f};

    const int NIT = (CELL == 0) ? 33 : 64;
    for (int it = 0; it < NIT; ++it) {
        const unsigned short* Asrc; int Astride; int k0;
        const unsigned short* Bsrc = nullptr;
        if (CELL == 0) {
            if (it == 0) { Asrc = WihH; Astride = 32; k0 = 0; }
            else { Asrc = WhhH; Astride = 1024; k0 = (it - 1) * 32; Bsrc = hB; }
        } else {
            if (it < 32) { Asrc = WihH; Astride = 1024; k0 = it * 32; Bsrc = hA; }
            else { Asrc = WhhH; Astride = 1024; k0 = (it - 32) * 32; Bsrc = hB; }
        }
        {
            int r = tid >> 2, c8 = (tid & 3) * 8;
            gld16(Asrc + (size_t)(m0 + r) * Astride + k0 + c8, &Ab[tid * 8]);
            gld16(Asrc + (size_t)(m0 + 64 + r) * Astride + k0 + c8, &Ab[2048 + tid * 8]);
            if (Bsrc) gld16(Bsrc + (size_t)(b0 + r) * 1024 + k0 + c8, &Bb[tid * 8]);
        }
        __syncthreads();
        const unsigned short* Bu = (CELL == 0 && it == 0) ? Xb : Bb;
        short8 af[4], bfr[2];
        #pragma unroll
        for (int mf = 0; mf < 4; ++mf)
            af[mf] = *(const short8*)&Ab[(wm * 64 + mf * 16 + (lane & 15)) * 32 + (lane >> 4) * 8];
        #pragma unroll
        for (int nf = 0; nf < 2; ++nf)
            bfr[nf] = *(const short8*)&Bu[(wn * 32 + nf * 16 + (lane & 15)) * 32 + (lane >> 4) * 8];
        #pragma unroll
        for (int mf = 0; mf < 4; ++mf)
            #pragma unroll
            for (int nf = 0; nf < 2; ++nf)
                acc[mf][nf] = __builtin_amdgcn_mfma_f32_16x16x32_bf16(af[mf], bfr[nf], acc[mf][nf], 0, 0, 0);
        __syncthreads();
    }

    // epilogue: lane owns (h = hc0+hl, b) with i,f,g,o in acc regs 0..3
    float pp[2][2] = {{0.f, 0.f}, {0.f, 0.f}};
    #pragma unroll
    for (int mf = 0; mf < 4; ++mf) {
        int hl = wm * 16 + mf * 4 + (lane >> 4);
        int h = hc0 + hl;
        f32x4 bs = *(const f32x4*)&biasH[h * 4];
        #pragma unroll
        for (int nf = 0; nf < 2; ++nf) {
            int b = b0 + wn * 32 + nf * 16 + (lane & 15);
            f32x4 v = acc[mf][nf];
            float gi = sigm(v.x + bs.x);
            float gf = sigm(v.y + bs.y);
            float gg = tanh_f(v.z + bs.z);
            float go = sigm(v.w + bs.w);
            size_t ci = (size_t)h * Bsz + b;
            float cn = gf * cws[ci] + gi * gg;
            cws[ci] = cn;
            float hn = go * tanh_f(cn);
            hOut[(size_t)b * Hsz + h] = f2bf(hn);
            if (CELL == 1) {
                pp[nf][0] += hn * wproj[h];
                pp[nf][1] += hn * wproj[Hsz + h];
            }
        }
    }
    if (CELL == 1) {
        #pragma unroll
        for (int nf = 0; nf < 2; ++nf)
            #pragma unroll
            for (int j = 0; j < 2; ++j) {
                float v = pp[nf][j];
                v += __shfl_xor(v, 16, 64);
                v += __shfl_xor(v, 32, 64);
                if (lane < 16) {
                    int b = b0 + wn * 32 + nf * 16 + lane;
                    atomicAdd(&pbufCur[b * 2 + j], v);
                }
            }
    }
}

// ---------------- tail: params[t=95] + mu/sigma table ----------------
__global__ void tail_params(const float* __restrict__ pbuf1, const float* __restrict__ bproj,
                            float* __restrict__ dout, float* __restrict__ musig) {
    int idx = blockIdx.x * 256 + threadIdx.x;
    if (idx >= Bsz * Psteps) return;
    int b = idx / Psteps, t = idx % Psteps;
    float p0, p1;
    if (t == Psteps - 1) {
        p0 = pbuf1[b * 2 + 0] + bproj[0];
        p1 = pbuf1[b * 2 + 1] + bproj[1];
        dout[(size_t)idx * 2 + 0] = p0;
        dout[(size_t)idx * 2 + 1] = p1;
    } else {
        p0 = dout[(size_t)idx * 2 + 0];
        p1 = dout[(size_t)idx * 2 + 1];
    }
    musig[(size_t)idx * 2 + 0] = p0;
    musig[(size_t)idx * 2 + 1] = softplusf(p1) + 1e-6f;
}

// ---------------- sample generation (out layout (S,B,P)) ----------------
__global__ __launch_bounds__(256) void gen_samples(const float* __restrict__ noise,
                                                   const float* __restrict__ musig,
                                                   float* __restrict__ outS) {
    __shared__ float tile[128][97];
    int s = blockIdx.x >> 3;
    int b0 = (blockIdx.x & 7) << 7;
    int tid = threadIdx.x;
    for (int e = tid; e < Psteps * 128; e += 256) {
        int tt = e >> 7, b = e & 127;
        tile[b][tt] = noise[((size_t)tt * Ssamp + s) * Bsz + b0 + b];
    }
    __syncthreads();
    int b = tid >> 1, t0 = (tid & 1) * 48;
    const float* ms = musig + ((size_t)(b0 + b) * Psteps + t0) * 2;
    float* op = outS + ((size_t)s * Bsz + b0 + b) * Psteps + t0;
    #pragma unroll 4
    for (int k = 0; k < 48; ++k) {
        float mu = ms[k * 2], sg = ms[k * 2 + 1];
        op[k] = mu + sg * tile[b][t0 + k];
    }
}

// ---------------- host ----------------
extern "C" void kernel_launch(void* const* d_in, const int* in_sizes, int n_in,
                              void* d_out, int out_size, void* d_ws, size_t ws_size,
                              hipStream_t stream) {
    const float* cov   = (const float*)d_in[0];
    const float* initv = (const float*)d_in[1];
    const float* noise = (const float*)d_in[2];
    const float* hinit = (const float*)d_in[3];
    const float* cinit = (const float*)d_in[4];
    const float* Wih0  = (const float*)d_in[5];
    const float* Whh0  = (const float*)d_in[6];
    const float* bih0  = (const float*)d_in[7];
    const float* bhh0  = (const float*)d_in[8];
    const float* Wih1  = (const float*)d_in[9];
    const float* Whh1  = (const float*)d_in[10];
    const float* bih1  = (const float*)d_in[11];
    const float* bhh1  = (const float*)d_in[12];
    const float* wproj = (const float*)d_in[13];
    const float* bproj = (const float*)d_in[14];
    float* dout = (float*)d_out;

    uint8_t* p = (uint8_t*)d_ws;
    auto alloc = [&](size_t bytes) { void* r = (void*)p; p += (bytes + 255) & ~(size_t)255; return r; };
    unsigned short* Whh0h = (unsigned short*)alloc((size_t)4096 * 1024 * 2);
    unsigned short* Wih1h = (unsigned short*)alloc((size_t)4096 * 1024 * 2);
    unsigned short* Whh1h = (unsigned short*)alloc((size_t)4096 * 1024 * 2);
    unsigned short* Wih0h = (unsigned short*)alloc((size_t)4096 * 32 * 2);
    float* bias0 = (float*)alloc(4096 * 4);
    float* bias1 = (float*)alloc(4096 * 4);
    unsigned short* hb0 = (unsigned short*)alloc((size_t)2 * 1024 * 1024 * 2);
    unsigned short* hb1 = (unsigned short*)alloc((size_t)2 * 1024 * 1024 * 2);
    float* c0 = (float*)alloc((size_t)1024 * 1024 * 4);
    float* c1 = (float*)alloc((size_t)1024 * 1024 * 4);
    float* pbuf = (float*)alloc((size_t)2 * 1024 * 2 * 4);
    float* musig = (float*)alloc((size_t)1024 * 96 * 2 * 4);

    prep_weights<<<2048, 256, 0, stream>>>(Wih0, Whh0, Wih1, Whh1, bih0, bhh0, bih1, bhh1,
                                           Wih0h, Whh0h, Wih1h, Whh1h, bias0, bias1);
    prep_state<<<2048, 256, 0, stream>>>(hinit, cinit, hb0, hb1, c0, c1);

    const size_t HB = (size_t)1024 * 1024;
    for (int t = 0; t < Psteps; ++t) {
        const float* pbPrev = pbuf + (size_t)((t + 1) & 1) * 2048;
        float* pbCur = pbuf + (size_t)(t & 1) * 2048;
        const unsigned short* h0p = hb0 + (size_t)(t & 1) * HB;
        unsigned short* h0n = hb0 + (size_t)((t + 1) & 1) * HB;
        const unsigned short* h1p = hb1 + (size_t)(t & 1) * HB;
        unsigned short* h1n = hb1 + (size_t)((t + 1) & 1) * HB;
        lstm_step<0><<<512, 256, 0, stream>>>(t, cov, initv, noise, bproj, wproj,
                                              Wih0h, Whh0h, bias0, nullptr, h0p, h0n, c0,
                                              pbPrev, pbCur, dout);
        lstm_step<1><<<512, 256, 0, stream>>>(t, cov, initv, noise, bproj, wproj,
                                              Wih1h, Whh1h, bias1, h0n, h1p, h1n, c1,
                                              pbPrev, pbCur, dout);
    }
    tail_params<<<384, 256, 0, stream>>>(pbuf + 2048, bproj, dout, musig);
    gen_samples<<<800, 256, 0, stream>>>(noise, musig, dout + (size_t)Bsz * Psteps * 2);
}

// Round 2
// 5152.533 us; speedup vs baseline: 1.1414x; 1.1414x over previous
//
#include <hip/hip_runtime.h>
#include <stdint.h>

#define Bsz 1024
#define Hsz 1024
#define Psteps 96
#define Ssamp 100
#define COVn 31

typedef __attribute__((ext_vector_type(8))) short short8;
typedef __attribute__((ext_vector_type(4))) float f32x4;

__device__ inline unsigned short f2bf(float f) {
    union { float f; unsigned u; } v; v.f = f;
    unsigned r = v.u + 0x7FFFu + ((v.u >> 16) & 1u);
    return (unsigned short)(r >> 16);
}

__device__ inline float sigm(float x) { return 1.f / (1.f + __expf(-x)); }
__device__ inline float tanh_f(float x) { return 2.f / (1.f + __expf(-2.f * x)) - 1.f; }
__device__ inline float softplusf(float x) {
    return fmaxf(x, 0.f) + log1pf(__expf(-fabsf(x)));
}

__device__ inline void gld16(const unsigned short* g, unsigned short* l) {
    auto gp = (const __attribute__((address_space(1))) unsigned int*)(const unsigned int*)g;
    auto lp = (__attribute__((address_space(3))) unsigned int*)(unsigned int*)l;
    __builtin_amdgcn_global_load_lds(gp, lp, 16, 0, 0);
}

// stage a 128x64 bf16 tile (16KB) into LDS, source-side XOR-swizzled.
// LDS layout: chunk c (= i*256+tid) at byte c*16; c = row*8 + s;
// content of (row,s) = global slot (s ^ (row&7)).
__device__ inline void stage_tile(const unsigned short* __restrict__ src, int rowStride,
                                  int row0, int k0, unsigned short* ldsBase, int tid) {
    #pragma unroll
    for (int i = 0; i < 4; ++i) {
        int c = i * 256 + tid;
        int row = c >> 3, s = c & 7;
        int col = ((s ^ (row & 7)) << 3) + k0;
        gld16(src + (size_t)(row0 + row) * rowStride + col, ldsBase + c * 8);
    }
}

// ---------------- prep kernels ----------------
// W0cat[4096][1088]: cols 0..31 = Wih0, 32..63 = 0, 64..1087 = Whh0 (gate rows interleaved g^=4h+g)
// W1cat[4096][2048]: cols 0..1023 = Wih1, 1024..2047 = Whh1
__global__ void prep_weights(const float* __restrict__ Wih0, const float* __restrict__ Whh0,
                             const float* __restrict__ Wih1, const float* __restrict__ Whh1,
                             const float* __restrict__ bih0, const float* __restrict__ bhh0,
                             const float* __restrict__ bih1, const float* __restrict__ bhh1,
                             unsigned short* __restrict__ W0cat, unsigned short* __restrict__ W1cat,
                             float* __restrict__ bias0, float* __restrict__ bias1) {
    const size_t N0 = (size_t)4096 * 1088;
    const size_t N1 = (size_t)4096 * 2048;
    const size_t total = N0 + N1 + 8192;
    for (size_t e = (size_t)blockIdx.x * 256 + threadIdx.x; e < total; e += (size_t)gridDim.x * 256) {
        if (e < N0) {
            int gh = (int)(e / 1088), col = (int)(e % 1088);
            int src = ((gh & 3) << 10) + (gh >> 2);
            float v;
            if (col < 32) v = Wih0[(size_t)src * 32 + col];
            else if (col < 64) v = 0.f;
            else v = Whh0[(size_t)src * 1024 + (col - 64)];
            W0cat[e] = f2bf(v);
        } else if (e < N0 + N1) {
            size_t m = e - N0;
            int gh = (int)(m >> 11), col = (int)(m & 2047);
            int src = ((gh & 3) << 10) + (gh >> 2);
            float v = (col < 1024) ? Wih1[(size_t)src * 1024 + col]
                                   : Whh1[(size_t)src * 1024 + (col - 1024)];
            W1cat[m] = f2bf(v);
        } else {
            size_t m = e - N0 - N1;             // 0..8191
            int which = (int)(m >> 12);
            int gh = (int)(m & 4095);
            int src = ((gh & 3) << 10) + (gh >> 2);
            if (which == 0) bias0[gh] = bih0[src] + bhh0[src];
            else            bias1[gh] = bih1[src] + bhh1[src];
        }
    }
}

__global__ void prep_state(const float* __restrict__ hinit, const float* __restrict__ cinit,
                           unsigned short* __restrict__ hb0, unsigned short* __restrict__ hb1,
                           float* __restrict__ c0, float* __restrict__ c1) {
    const size_t NM = (size_t)1024 * 1024;
    for (size_t e = (size_t)blockIdx.x * 256 + threadIdx.x; e < 4 * NM; e += (size_t)gridDim.x * 256) {
        if (e < NM) {
            hb0[e] = f2bf(hinit[e]);                       // h stored [B][H] bf16
        } else if (e < 2 * NM) {
            hb1[e - NM] = f2bf(hinit[e]);
        } else if (e < 3 * NM) {
            size_t j = e - 2 * NM; int h = (int)(j >> 10), b = (int)(j & 1023);
            c0[j] = cinit[(size_t)b * 1024 + h];           // c stored [H][B] f32
        } else {
            size_t j = e - 3 * NM; int h = (int)(j >> 10), b = (int)(j & 1023);
            c1[j] = cinit[NM + (size_t)b * 1024 + h];
        }
    }
}

// ---------------- LSTM step GEMM kernel ----------------
// gates^T = W_cat (M=4096, g^=4h+g interleaved) x input^T (N=1024 batch)
// tile 128x128, BK=64, grid 32m x 8n = 256 blocks, 4 waves (2x2), wave tile 64x64.
// LDS 64KB: Ab[2]=0/16K, Bb[2]=32K/48K, double buffered, XOR-swizzled slots.
template<int CELL>
__global__ __launch_bounds__(256) void lstm_step(
        int t,
        const float* __restrict__ cov, const float* __restrict__ initv,
        const float* __restrict__ noise, const float* __restrict__ bproj,
        const float* __restrict__ wproj,
        const unsigned short* __restrict__ WA,   // W0cat or W1cat
        const float* __restrict__ biasH,
        const unsigned short* __restrict__ hA,   // cell1: h0_new (first K half)
        const unsigned short* __restrict__ hB,   // cell0: h0_prev; cell1: h1_prev
        unsigned short* __restrict__ hOut,
        float* __restrict__ cws,
        float* __restrict__ pbufPartial,         // [32 m][1024 b][2]
        float* __restrict__ outParams) {
    __shared__ __align__(16) char smem[65536];

    const int tid = threadIdx.x;
    const int m_tile = blockIdx.x & 31;          // xcd = blockIdx%8 = m_tile%8 -> A L2-resident
    const int n_tile = blockIdx.x >> 5;
    const int m0 = m_tile * 128;                 // gate-row base
    const int hc0 = m_tile * 32;                 // h base (128 gates / 4)
    const int b0 = n_tile * 128;
    const int lane = tid & 63;
    const int wid = tid >> 6;
    const int wm = wid >> 1, wn = wid & 1;

    // ---------- prologue ----------
    if (CELL == 0) {
        float* pj = (float*)(smem + 16384);          // [128][2] in Ab1 (dead before loop stage(1))
        float* curF = (float*)(smem + 16384 + 2048); // [128]
        if (t > 0) {
            int bl = tid >> 1, j = tid & 1;
            float s = bproj[j];
            #pragma unroll 8
            for (int m = 0; m < 32; ++m)
                s += pbufPartial[(size_t)((m << 10) + b0 + bl) * 2 + j];
            pj[tid] = s;
            if (m_tile == 0)
                outParams[((size_t)(b0 + bl) * Psteps + (t - 1)) * 2 + j] = s;
        }
        __syncthreads();
        if (tid < 128) {
            float cu;
            if (t == 0) {
                cu = initv[b0 + tid];
            } else {
                float p0 = pj[tid * 2 + 0], p1 = pj[tid * 2 + 1];
                cu = p0 + (softplusf(p1) + 1e-6f) * noise[(size_t)(t - 1) * (Ssamp * Bsz) + b0 + tid];
            }
            curF[tid] = cu;
        }
        __syncthreads();
        // build X tile (iter0 B): cols 0..31 = [cur, cov0..30], cols 32..63 = 0 (swizzled write)
        #pragma unroll
        for (int i = 0; i < 4; ++i) {
            int c = i * 256 + tid;
            int row = c >> 3, s = c & 7;
            int ts = s ^ (row & 7);
            short8 v;
            if (ts < 4) {
                const float* cr = cov + ((size_t)(b0 + row) * Psteps + t) * COVn;
                #pragma unroll
                for (int e = 0; e < 8; ++e) {
                    int col = ts * 8 + e;
                    float x = (col == 0) ? curF[row] : cr[col - 1];
                    v[e] = (short)f2bf(x);
                }
            } else {
                v = (short8){0, 0, 0, 0, 0, 0, 0, 0};
            }
            *(short8*)(smem + 32768 + c * 16) = v;
        }
        stage_tile(WA, 1088, m0, 0, (unsigned short*)(smem + 0), tid);
    } else {
        stage_tile(WA, 2048, m0, 0, (unsigned short*)(smem + 0), tid);
        stage_tile(hA, 1024, b0, 0, (unsigned short*)(smem + 32768), tid);
    }
    __syncthreads();   // drains vmcnt + lgkm

    f32x4 acc[4][4];
    #pragma unroll
    for (int i = 0; i < 4; ++i)
        #pragma unroll
        for (int j = 0; j < 4; ++j) acc[i][j] = (f32x4){0.f, 0.f, 0.f, 0.f};

    const int NIT = (CELL == 0) ? 17 : 32;
    int cur = 0;
    for (int it = 0; it < NIT; ++it) {
        int nxt = cur ^ 1;
        // stage it+1 into the other buffer (issued BEFORE compute -> overlaps)
        if (it + 1 < NIT) {
            unsigned short* AbN = (unsigned short*)(smem + nxt * 16384);
            unsigned short* BbN = (unsigned short*)(smem + 32768 + nxt * 16384);
            if (CELL == 0) {
                stage_tile(WA, 1088, m0, (it + 1) * 64, AbN, tid);
                stage_tile(hB, 1024, b0, it * 64, BbN, tid);        // A col 64+j <-> h col j
            } else {
                stage_tile(WA, 2048, m0, (it + 1) * 64, AbN, tid);
                const unsigned short* Bs = (it + 1 < 16) ? hA : hB;
                int bk = (it + 1 < 16) ? (it + 1) * 64 : (it + 1 - 16) * 64;
                stage_tile(Bs, 1024, b0, bk, BbN, tid);
            }
        }
        // compute from buf[cur]
        const char* Abuf = smem + cur * 16384;
        const char* Bbuf = smem + 32768 + cur * 16384;
        #pragma unroll
        for (int kh = 0; kh < 2; ++kh) {
            short8 af[4], bq[4];
            #pragma unroll
            for (int mf = 0; mf < 4; ++mf) {
                int row = wm * 64 + mf * 16 + (lane & 15);
                int slot = (kh * 4 + (lane >> 4)) ^ (row & 7);
                af[mf] = *(const short8*)(Abuf + row * 128 + slot * 16);
            }
            #pragma unroll
            for (int nf = 0; nf < 4; ++nf) {
                int row = wn * 64 + nf * 16 + (lane & 15);
                int slot = (kh * 4 + (lane >> 4)) ^ (row & 7);
                bq[nf] = *(const short8*)(Bbuf + row * 128 + slot * 16);
            }
            #pragma unroll
            for (int mf = 0; mf < 4; ++mf)
                #pragma unroll
                for (int nf = 0; nf < 4; ++nf)
                    acc[mf][nf] = __builtin_amdgcn_mfma_f32_16x16x32_bf16(af[mf], bq[nf], acc[mf][nf], 0, 0, 0);
        }
        __syncthreads();
        cur = nxt;
    }

    // ---------- epilogue ----------
    unsigned short* Ht = (unsigned short*)smem;      // [128 b][40] bf16 (pad for banks/alignment)
    float* part = (float*)(smem + 32768);            // [2 wm][128 b][2 j]
    float pp[4][2];
    if (CELL == 1) {
        #pragma unroll
        for (int nf = 0; nf < 4; ++nf) { pp[nf][0] = 0.f; pp[nf][1] = 0.f; }
    }
    #pragma unroll
    for (int mf = 0; mf < 4; ++mf) {
        int hl = wm * 16 + mf * 4 + (lane >> 4);
        int h = hc0 + hl;
        f32x4 bs = *(const f32x4*)&biasH[h * 4];
        #pragma unroll
        for (int nf = 0; nf < 4; ++nf) {
            int bl = wn * 64 + nf * 16 + (lane & 15);
            int b = b0 + bl;
            f32x4 v = acc[mf][nf];
            float gi = sigm(v.x + bs.x);
            float gf = sigm(v.y + bs.y);
            float gg = tanh_f(v.z + bs.z);
            float go = sigm(v.w + bs.w);
            size_t ci = (size_t)h * Bsz + b;
            float cn = gf * cws[ci] + gi * gg;
            cws[ci] = cn;
            float hn = go * tanh_f(cn);
            Ht[bl * 40 + hl] = f2bf(hn);
            if (CELL == 1) {
                pp[nf][0] += hn * wproj[h];
                pp[nf][1] += hn * wproj[Hsz + h];
            }
        }
    }
    if (CELL == 1) {
        #pragma unroll
        for (int nf = 0; nf < 4; ++nf)
            #pragma unroll
            for (int j = 0; j < 2; ++j) {
                float v = pp[nf][j];
                v += __shfl_xor(v, 16, 64);
                v += __shfl_xor(v, 32, 64);
                if (lane < 16)
                    part[((wm * 128) + wn * 64 + nf * 16 + lane) * 2 + j] = v;
            }
    }
    __syncthreads();
    {   // coalesced h write: 128 rows x 64B contiguous
        int row = tid >> 1, hf = tid & 1;
        short8 v0 = *(const short8*)&Ht[row * 40 + hf * 16];
        short8 v1 = *(const short8*)&Ht[row * 40 + hf * 16 + 8];
        *(short8*)&hOut[(size_t)(b0 + row) * Hsz + hc0 + hf * 16] = v0;
        *(short8*)&hOut[(size_t)(b0 + row) * Hsz + hc0 + hf * 16 + 8] = v1;
    }
    if (CELL == 1) {
        int bl = tid >> 1, j = tid & 1;
        pbufPartial[((size_t)m_tile * 1024 + b0 + bl) * 2 + j] =
            part[bl * 2 + j] + part[(128 + bl) * 2 + j];
    }
}

// ---------------- tail: params[t=95] + mu/sigma table ----------------
__global__ void tail_params(const float* __restrict__ pPart, const float* __restrict__ bproj,
                            float* __restrict__ dout, float* __restrict__ musig) {
    int idx = blockIdx.x * 256 + threadIdx.x;
    if (idx >= Bsz * Psteps) return;
    int b = idx / Psteps, t = idx % Psteps;
    float p0, p1;
    if (t == Psteps - 1) {
        p0 = bproj[0]; p1 = bproj[1];
        #pragma unroll 8
        for (int m = 0; m < 32; ++m) {
            p0 += pPart[(size_t)((m << 10) + b) * 2 + 0];
            p1 += pPart[(size_t)((m << 10) + b) * 2 + 1];
        }
        dout[(size_t)idx * 2 + 0] = p0;
        dout[(size_t)idx * 2 + 1] = p1;
    } else {
        p0 = dout[(size_t)idx * 2 + 0];
        p1 = dout[(size_t)idx * 2 + 1];
    }
    musig[(size_t)idx * 2 + 0] = p0;
    musig[(size_t)idx * 2 + 1] = softplusf(p1) + 1e-6f;
}

// ---------------- sample generation (out layout (S,B,P)) ----------------
__global__ __launch_bounds__(256) void gen_samples(const float* __restrict__ noise,
                                                   const float* __restrict__ musig,
                                                   float* __restrict__ outS) {
    __shared__ float tile[128][97];
    int s = blockIdx.x >> 3;
    int b0 = (blockIdx.x & 7) << 7;
    int tid = threadIdx.x;
    for (int e = tid; e < Psteps * 128; e += 256) {
        int tt = e >> 7, b = e & 127;
        tile[b][tt] = noise[((size_t)tt * Ssamp + s) * Bsz + b0 + b];
    }
    __syncthreads();
    int b = tid >> 1, t0 = (tid & 1) * 48;
    const float* ms = musig + ((size_t)(b0 + b) * Psteps + t0) * 2;
    float* op = outS + ((size_t)s * Bsz + b0 + b) * Psteps + t0;
    #pragma unroll 4
    for (int k = 0; k < 48; ++k) {
        float mu = ms[k * 2], sg = ms[k * 2 + 1];
        op[k] = mu + sg * tile[b][t0 + k];
    }
}

// ---------------- host ----------------
extern "C" void kernel_launch(void* const* d_in, const int* in_sizes, int n_in,
                              void* d_out, int out_size, void* d_ws, size_t ws_size,
                              hipStream_t stream) {
    const float* cov   = (const float*)d_in[0];
    const float* initv = (const float*)d_in[1];
    const float* noise = (const float*)d_in[2];
    const float* hinit = (const float*)d_in[3];
    const float* cinit = (const float*)d_in[4];
    const float* Wih0  = (const float*)d_in[5];
    const float* Whh0  = (const float*)d_in[6];
    const float* bih0  = (const float*)d_in[7];
    const float* bhh0  = (const float*)d_in[8];
    const float* Wih1  = (const float*)d_in[9];
    const float* Whh1  = (const float*)d_in[10];
    const float* bih1  = (const float*)d_in[11];
    const float* bhh1  = (const float*)d_in[12];
    const float* wproj = (const float*)d_in[13];
    const float* bproj = (const float*)d_in[14];
    float* dout = (float*)d_out;

    uint8_t* p = (uint8_t*)d_ws;
    auto alloc = [&](size_t bytes) { void* r = (void*)p; p += (bytes + 255) & ~(size_t)255; return r; };
    unsigned short* W0cat = (unsigned short*)alloc((size_t)4096 * 1088 * 2);
    unsigned short* W1cat = (unsigned short*)alloc((size_t)4096 * 2048 * 2);
    float* bias0 = (float*)alloc(4096 * 4);
    float* bias1 = (float*)alloc(4096 * 4);
    unsigned short* hb0 = (unsigned short*)alloc((size_t)2 * 1024 * 1024 * 2 + 256);
    unsigned short* hb1 = (unsigned short*)alloc((size_t)2 * 1024 * 1024 * 2 + 256);
    float* c0 = (float*)alloc((size_t)1024 * 1024 * 4);
    float* c1 = (float*)alloc((size_t)1024 * 1024 * 4);
    float* pbufPartial = (float*)alloc((size_t)32 * 1024 * 2 * 4);
    float* musig = (float*)alloc((size_t)1024 * 96 * 2 * 4);

    prep_weights<<<2048, 256, 0, stream>>>(Wih0, Whh0, Wih1, Whh1, bih0, bhh0, bih1, bhh1,
                                           W0cat, W1cat, bias0, bias1);
    prep_state<<<2048, 256, 0, stream>>>(hinit, cinit, hb0, hb1, c0, c1);

    const size_t HB = (size_t)1024 * 1024;
    for (int t = 0; t < Psteps; ++t) {
        const unsigned short* h0p = hb0 + (size_t)(t & 1) * HB;
        unsigned short* h0n = hb0 + (size_t)((t + 1) & 1) * HB;
        const unsigned short* h1p = hb1 + (size_t)(t & 1) * HB;
        unsigned short* h1n = hb1 + (size_t)((t + 1) & 1) * HB;
        lstm_step<0><<<256, 256, 0, stream>>>(t, cov, initv, noise, bproj, wproj,
                                              W0cat, bias0, nullptr, h0p, h0n, c0,
                                              pbufPartial, dout);
        lstm_step<1><<<256, 256, 0, stream>>>(t, cov, initv, noise, bproj, wproj,
                                              W1cat, bias1, h0n, h1p, h1n, c1,
                                              pbufPartial, dout);
    }
    tail_params<<<384, 256, 0, stream>>>(pbufPartial, bproj, dout, musig);
    gen_samples<<<800, 256, 0, stream>>>(noise, musig, dout + (size_t)Bsz * Psteps * 2);
}

// Round 3
// 4681.886 us; speedup vs baseline: 1.2562x; 1.1005x over previous
//
#include <hip/hip_runtime.h>
#include <stdint.h>

#define Bsz 1024
#define Hsz 1024
#define Psteps 96
#define Ssamp 100
#define COVn 31

typedef __attribute__((ext_vector_type(8))) short short8;
typedef __attribute__((ext_vector_type(4))) float f32x4;

__device__ inline unsigned short f2bf(float f) {
    union { float f; unsigned u; } v; v.f = f;
    unsigned r = v.u + 0x7FFFu + ((v.u >> 16) & 1u);
    return (unsigned short)(r >> 16);
}

__device__ inline float sigm(float x) { return 1.f / (1.f + __expf(-x)); }
__device__ inline float tanh_f(float x) { return 2.f / (1.f + __expf(-2.f * x)) - 1.f; }
__device__ inline float softplusf(float x) {
    return fmaxf(x, 0.f) + log1pf(__expf(-fabsf(x)));
}

__device__ inline void gld16(const unsigned short* g, unsigned short* l) {
    auto gp = (const __attribute__((address_space(1))) unsigned int*)(const unsigned int*)g;
    auto lp = (__attribute__((address_space(3))) unsigned int*)(unsigned int*)l;
    __builtin_amdgcn_global_load_lds(gp, lp, 16, 0, 0);
}

// stage a 128x64 bf16 tile (16KB) into LDS, source-side XOR-swizzled.
// LDS layout: chunk c (= i*256+tid) at byte c*16; c = row*8 + s;
// content of (row,s) = global slot (s ^ (row&7)).
__device__ inline void stage_tile(const unsigned short* __restrict__ src, int rowStride,
                                  int row0, int k0, unsigned short* ldsBase, int tid) {
    #pragma unroll
    for (int i = 0; i < 4; ++i) {
        int c = i * 256 + tid;
        int row = c >> 3, s = c & 7;
        int col = ((s ^ (row & 7)) << 3) + k0;
        gld16(src + (size_t)(row0 + row) * rowStride + col, ldsBase + c * 8);
    }
}

// ---------------- prep kernels ----------------
// W0cat[4096][1088]: cols 0..31 = Wih0, 32..63 = 0, 64..1087 = Whh0 (gate rows interleaved g^=4h+g)
// W1cat[4096][2048]: cols 0..1023 = Wih1, 1024..2047 = Whh1
__global__ void prep_weights(const float* __restrict__ Wih0, const float* __restrict__ Whh0,
                             const float* __restrict__ Wih1, const float* __restrict__ Whh1,
                             const float* __restrict__ bih0, const float* __restrict__ bhh0,
                             const float* __restrict__ bih1, const float* __restrict__ bhh1,
                             unsigned short* __restrict__ W0cat, unsigned short* __restrict__ W1cat,
                             float* __restrict__ bias0, float* __restrict__ bias1) {
    const size_t N0 = (size_t)4096 * 1088;
    const size_t N1 = (size_t)4096 * 2048;
    const size_t total = N0 + N1 + 8192;
    for (size_t e = (size_t)blockIdx.x * 256 + threadIdx.x; e < total; e += (size_t)gridDim.x * 256) {
        if (e < N0) {
            int gh = (int)(e / 1088), col = (int)(e % 1088);
            int src = ((gh & 3) << 10) + (gh >> 2);
            float v;
            if (col < 32) v = Wih0[(size_t)src * 32 + col];
            else if (col < 64) v = 0.f;
            else v = Whh0[(size_t)src * 1024 + (col - 64)];
            W0cat[e] = f2bf(v);
        } else if (e < N0 + N1) {
            size_t m = e - N0;
            int gh = (int)(m >> 11), col = (int)(m & 2047);
            int src = ((gh & 3) << 10) + (gh >> 2);
            float v = (col < 1024) ? Wih1[(size_t)src * 1024 + col]
                                   : Whh1[(size_t)src * 1024 + (col - 1024)];
            W1cat[m] = f2bf(v);
        } else {
            size_t m = e - N0 - N1;             // 0..8191
            int which = (int)(m >> 12);
            int gh = (int)(m & 4095);
            int src = ((gh & 3) << 10) + (gh >> 2);
            if (which == 0) bias0[gh] = bih0[src] + bhh0[src];
            else            bias1[gh] = bih1[src] + bhh1[src];
        }
    }
}

__global__ void prep_state(const float* __restrict__ hinit, const float* __restrict__ cinit,
                           unsigned short* __restrict__ hb0, unsigned short* __restrict__ hb1,
                           float* __restrict__ c0, float* __restrict__ c1) {
    const size_t NM = (size_t)1024 * 1024;
    for (size_t e = (size_t)blockIdx.x * 256 + threadIdx.x; e < 4 * NM; e += (size_t)gridDim.x * 256) {
        if (e < NM) {
            hb0[e] = f2bf(hinit[e]);                       // h stored [B][H] bf16
        } else if (e < 2 * NM) {
            hb1[e - NM] = f2bf(hinit[e]);
        } else if (e < 3 * NM) {
            size_t j = e - 2 * NM; int h = (int)(j >> 10), b = (int)(j & 1023);
            c0[j] = cinit[(size_t)b * 1024 + h];           // c stored [H][B] f32
        } else {
            size_t j = e - 3 * NM; int h = (int)(j >> 10), b = (int)(j & 1023);
            c1[j] = cinit[NM + (size_t)b * 1024 + h];
        }
    }
}

// ---------------- LSTM step GEMM kernel ----------------
// gates^T = W_cat (M=4096, g^=4h+g interleaved) x input^T (N=1024 batch)
// tile 128x128, BK=64, grid 32m x 8n = 256 blocks, 4 waves (2x2), wave tile 64x64.
// LDS 128KB: A bufs j&3 at 0..64K, B bufs at 64K..128K. Prefetch depth 2,
// counted vmcnt (16/8/0), ONE raw s_barrier per iter (quad buffer makes it safe).
template<int CELL>
__global__ __launch_bounds__(256) void lstm_step(
        int t,
        const float* __restrict__ cov, const float* __restrict__ initv,
        const float* __restrict__ noise, const float* __restrict__ bproj,
        const float* __restrict__ wproj,
        const unsigned short* __restrict__ WA,   // W0cat or W1cat
        const float* __restrict__ biasH,
        const unsigned short* __restrict__ hA,   // cell1: h0_new (first K half)
        const unsigned short* __restrict__ hB,   // cell0: h0_prev; cell1: h1_prev
        unsigned short* __restrict__ hOut,
        float* __restrict__ cws,
        float* __restrict__ pbufPartial,         // [32 m][1024 b][2]
        float* __restrict__ outParams) {
    __shared__ __align__(16) char smem[131072];

    const int tid = threadIdx.x;
    const int m_tile = blockIdx.x & 31;          // xcd = blockIdx%8 = m_tile%8 -> A L2-resident
    const int n_tile = blockIdx.x >> 5;
    const int m0 = m_tile * 128;                 // gate-row base
    const int hc0 = m_tile * 32;                 // h base (128 gates / 4)
    const int b0 = n_tile * 128;
    const int lane = tid & 63;
    const int wid = tid >> 6;
    const int wm = wid >> 1, wn = wid & 1;
    const int NIT = (CELL == 0) ? 17 : 32;

    auto stageIt = [&](int j) {
        unsigned short* Ab = (unsigned short*)(smem + (j & 3) * 16384);
        unsigned short* Bb = (unsigned short*)(smem + 65536 + (j & 3) * 16384);
        if (CELL == 0) {
            stage_tile(WA, 1088, m0, j * 64, Ab, tid);
            if (j > 0) stage_tile(hB, 1024, b0, (j - 1) * 64, Bb, tid);
        } else {
            stage_tile(WA, 2048, m0, j * 64, Ab, tid);
            if (j < 16) stage_tile(hA, 1024, b0, j * 64, Bb, tid);
            else        stage_tile(hB, 1024, b0, (j - 16) * 64, Bb, tid);
        }
    };

    // ---------- prologue: issue bufs 0,1; build X (cell0) ----------
    stageIt(0);
    stageIt(1);
    if (CELL == 0) {
        float* pj = (float*)(smem + 114688);          // B3 region (staged only at iter 1 -> safe)
        float* curF = (float*)(smem + 114688 + 2048);
        if (t > 0) {
            int bl = tid >> 1, j = tid & 1;
            float s = bproj[j];
            #pragma unroll 8
            for (int m = 0; m < 32; ++m)
                s += pbufPartial[(size_t)((m << 10) + b0 + bl) * 2 + j];
            pj[tid] = s;
            if (m_tile == 0)
                outParams[((size_t)(b0 + bl) * Psteps + (t - 1)) * 2 + j] = s;
        }
        __syncthreads();
        if (tid < 128) {
            float cu;
            if (t == 0) {
                cu = initv[b0 + tid];
            } else {
                float p0 = pj[tid * 2 + 0], p1 = pj[tid * 2 + 1];
                cu = p0 + (softplusf(p1) + 1e-6f) * noise[(size_t)(t - 1) * (Ssamp * Bsz) + b0 + tid];
            }
            curF[tid] = cu;
        }
        __syncthreads();
        // build X tile into B buffer 0: cols 0..31 = [cur, cov0..30], 32..63 = 0 (swizzled)
        #pragma unroll
        for (int i = 0; i < 4; ++i) {
            int c = i * 256 + tid;
            int row = c >> 3, s = c & 7;
            int ts = s ^ (row & 7);
            short8 v;
            if (ts < 4) {
                const float* cr = cov + ((size_t)(b0 + row) * Psteps + t) * COVn;
                #pragma unroll
                for (int e = 0; e < 8; ++e) {
                    int col = ts * 8 + e;
                    float x = (col == 0) ? curF[row] : cr[col - 1];
                    v[e] = (short)f2bf(x);
                }
            } else {
                v = (short8){0, 0, 0, 0, 0, 0, 0, 0};
            }
            *(short8*)(smem + 65536 + c * 16) = v;
        }
    }
    __syncthreads();   // drains prologue loads + X writes; bufs 0,1 ready

    f32x4 acc[4][4];
    #pragma unroll
    for (int i = 0; i < 4; ++i)
        #pragma unroll
        for (int j = 0; j < 4; ++j) acc[i][j] = (f32x4){0.f, 0.f, 0.f, 0.f};

    // ---------- main loop: single barrier, counted vmcnt ----------
    for (int it = 0; it < NIT; ++it) {
        if (it + 2 < NIT) stageIt(it + 2);
        int rem = NIT - 1 - it;
        if (rem >= 2)      asm volatile("s_waitcnt vmcnt(16)" ::: "memory");
        else if (rem == 1) asm volatile("s_waitcnt vmcnt(8)" ::: "memory");
        else               asm volatile("s_waitcnt vmcnt(0)" ::: "memory");
        __builtin_amdgcn_s_barrier();
        asm volatile("" ::: "memory");
        const char* Abuf = smem + (it & 3) * 16384;
        const char* Bbuf = smem + 65536 + (it & 3) * 16384;
        __builtin_amdgcn_s_setprio(1);
        #pragma unroll
        for (int kh = 0; kh < 2; ++kh) {
            short8 af[4], bq[4];
            #pragma unroll
            for (int mf = 0; mf < 4; ++mf) {
                int row = wm * 64 + mf * 16 + (lane & 15);
                int slot = (kh * 4 + (lane >> 4)) ^ (row & 7);
                af[mf] = *(const short8*)(Abuf + row * 128 + slot * 16);
            }
            #pragma unroll
            for (int nf = 0; nf < 4; ++nf) {
                int row = wn * 64 + nf * 16 + (lane & 15);
                int slot = (kh * 4 + (lane >> 4)) ^ (row & 7);
                bq[nf] = *(const short8*)(Bbuf + row * 128 + slot * 16);
            }
            #pragma unroll
            for (int mf = 0; mf < 4; ++mf)
                #pragma unroll
                for (int nf = 0; nf < 4; ++nf)
                    acc[mf][nf] = __builtin_amdgcn_mfma_f32_16x16x32_bf16(af[mf], bq[nf], acc[mf][nf], 0, 0, 0);
        }
        __builtin_amdgcn_s_setprio(0);
    }
    __syncthreads();   // all waves done with LDS buffers before epilogue reuse

    // ---------- epilogue ----------
    unsigned short* Ht = (unsigned short*)smem;      // [128 b][40] bf16
    float* part = (float*)(smem + 16384);            // [2 wm][128 b][2 j]
    float pp[4][2];
    if (CELL == 1) {
        #pragma unroll
        for (int nf = 0; nf < 4; ++nf) { pp[nf][0] = 0.f; pp[nf][1] = 0.f; }
    }
    #pragma unroll
    for (int mf = 0; mf < 4; ++mf) {
        int hl = wm * 16 + mf * 4 + (lane >> 4);
        int h = hc0 + hl;
        f32x4 bs = *(const f32x4*)&biasH[h * 4];
        #pragma unroll
        for (int nf = 0; nf < 4; ++nf) {
            int bl = wn * 64 + nf * 16 + (lane & 15);
            int b = b0 + bl;
            f32x4 v = acc[mf][nf];
            float gi = sigm(v.x + bs.x);
            float gf = sigm(v.y + bs.y);
            float gg = tanh_f(v.z + bs.z);
            float go = sigm(v.w + bs.w);
            size_t ci = (size_t)h * Bsz + b;
            float cn = gf * cws[ci] + gi * gg;
            cws[ci] = cn;
            float hn = go * tanh_f(cn);
            Ht[bl * 40 + hl] = f2bf(hn);
            if (CELL == 1) {
                pp[nf][0] += hn * wproj[h];
                pp[nf][1] += hn * wproj[Hsz + h];
            }
        }
    }
    if (CELL == 1) {
        #pragma unroll
        for (int nf = 0; nf < 4; ++nf)
            #pragma unroll
            for (int j = 0; j < 2; ++j) {
                float v = pp[nf][j];
                v += __shfl_xor(v, 16, 64);
                v += __shfl_xor(v, 32, 64);
                if (lane < 16)
                    part[((wm * 128) + wn * 64 + nf * 16 + lane) * 2 + j] = v;
            }
    }
    __syncthreads();
    {   // coalesced h write: 128 rows x 64B contiguous
        int row = tid >> 1, hf = tid & 1;
        short8 v0 = *(const short8*)&Ht[row * 40 + hf * 16];
        short8 v1 = *(const short8*)&Ht[row * 40 + hf * 16 + 8];
        *(short8*)&hOut[(size_t)(b0 + row) * Hsz + hc0 + hf * 16] = v0;
        *(short8*)&hOut[(size_t)(b0 + row) * Hsz + hc0 + hf * 16 + 8] = v1;
    }
    if (CELL == 1) {
        int bl = tid >> 1, j = tid & 1;
        pbufPartial[((size_t)m_tile * 1024 + b0 + bl) * 2 + j] =
            part[bl * 2 + j] + part[(128 + bl) * 2 + j];
    }
}

// ---------------- tail: params[t=95] + mu/sigma table ----------------
__global__ void tail_params(const float* __restrict__ pPart, const float* __restrict__ bproj,
                            float* __restrict__ dout, float* __restrict__ musig) {
    int idx = blockIdx.x * 256 + threadIdx.x;
    if (idx >= Bsz * Psteps) return;
    int b = idx / Psteps, t = idx % Psteps;
    float p0, p1;
    if (t == Psteps - 1) {
        p0 = bproj[0]; p1 = bproj[1];
        #pragma unroll 8
        for (int m = 0; m < 32; ++m) {
            p0 += pPart[(size_t)((m << 10) + b) * 2 + 0];
            p1 += pPart[(size_t)((m << 10) + b) * 2 + 1];
        }
        dout[(size_t)idx * 2 + 0] = p0;
        dout[(size_t)idx * 2 + 1] = p1;
    } else {
        p0 = dout[(size_t)idx * 2 + 0];
        p1 = dout[(size_t)idx * 2 + 1];
    }
    musig[(size_t)idx * 2 + 0] = p0;
    musig[(size_t)idx * 2 + 1] = softplusf(p1) + 1e-6f;
}

// ---------------- sample generation (out layout (S,B,P)) ----------------
// grid = 100 s * 64 batch-chunks = 6400 blocks of (s, 16 batch)
__global__ __launch_bounds__(256) void gen_samples(const float* __restrict__ noise,
                                                   const float* __restrict__ musig,
                                                   float* __restrict__ outS) {
    __shared__ float tile[16][97];
    int s = blockIdx.x >> 6;
    int b0 = (blockIdx.x & 63) << 4;
    int tid = threadIdx.x;
    for (int e = tid; e < Psteps * 16; e += 256) {
        int tt = e >> 4, b = e & 15;
        tile[b][tt] = noise[((size_t)tt * Ssamp + s) * Bsz + b0 + b];
    }
    __syncthreads();
    int b = tid >> 4, t0 = (tid & 15) * 6;
    const float* ms = musig + ((size_t)(b0 + b) * Psteps + t0) * 2;
    float* op = outS + ((size_t)s * Bsz + b0 + b) * Psteps + t0;
    #pragma unroll
    for (int k = 0; k < 6; ++k) {
        op[k] = ms[k * 2] + ms[k * 2 + 1] * tile[b][t0 + k];
    }
}

// ---------------- host ----------------
extern "C" void kernel_launch(void* const* d_in, const int* in_sizes, int n_in,
                              void* d_out, int out_size, void* d_ws, size_t ws_size,
                              hipStream_t stream) {
    const float* cov   = (const float*)d_in[0];
    const float* initv = (const float*)d_in[1];
    const float* noise = (const float*)d_in[2];
    const float* hinit = (const float*)d_in[3];
    const float* cinit = (const float*)d_in[4];
    const float* Wih0  = (const float*)d_in[5];
    const float* Whh0  = (const float*)d_in[6];
    const float* bih0  = (const float*)d_in[7];
    const float* bhh0  = (const float*)d_in[8];
    const float* Wih1  = (const float*)d_in[9];
    const float* Whh1  = (const float*)d_in[10];
    const float* bih1  = (const float*)d_in[11];
    const float* bhh1  = (const float*)d_in[12];
    const float* wproj = (const float*)d_in[13];
    const float* bproj = (const float*)d_in[14];
    float* dout = (float*)d_out;

    uint8_t* p = (uint8_t*)d_ws;
    auto alloc = [&](size_t bytes) { void* r = (void*)p; p += (bytes + 255) & ~(size_t)255; return r; };
    unsigned short* W0cat = (unsigned short*)alloc((size_t)4096 * 1088 * 2);
    unsigned short* W1cat = (unsigned short*)alloc((size_t)4096 * 2048 * 2);
    float* bias0 = (float*)alloc(4096 * 4);
    float* bias1 = (float*)alloc(4096 * 4);
    unsigned short* hb0 = (unsigned short*)alloc((size_t)2 * 1024 * 1024 * 2 + 256);
    unsigned short* hb1 = (unsigned short*)alloc((size_t)2 * 1024 * 1024 * 2 + 256);
    float* c0 = (float*)alloc((size_t)1024 * 1024 * 4);
    float* c1 = (float*)alloc((size_t)1024 * 1024 * 4);
    float* pbufPartial = (float*)alloc((size_t)32 * 1024 * 2 * 4);
    float* musig = (float*)alloc((size_t)1024 * 96 * 2 * 4);

    prep_weights<<<2048, 256, 0, stream>>>(Wih0, Whh0, Wih1, Whh1, bih0, bhh0, bih1, bhh1,
                                           W0cat, W1cat, bias0, bias1);
    prep_state<<<2048, 256, 0, stream>>>(hinit, cinit, hb0, hb1, c0, c1);

    const size_t HB = (size_t)1024 * 1024;
    for (int t = 0; t < Psteps; ++t) {
        const unsigned short* h0p = hb0 + (size_t)(t & 1) * HB;
        unsigned short* h0n = hb0 + (size_t)((t + 1) & 1) * HB;
        const unsigned short* h1p = hb1 + (size_t)(t & 1) * HB;
        unsigned short* h1n = hb1 + (size_t)((t + 1) & 1) * HB;
        lstm_step<0><<<256, 256, 0, stream>>>(t, cov, initv, noise, bproj, wproj,
                                              W0cat, bias0, nullptr, h0p, h0n, c0,
                                              pbufPartial, dout);
        lstm_step<1><<<256, 256, 0, stream>>>(t, cov, initv, noise, bproj, wproj,
                                              W1cat, bias1, h0n, h1p, h1n, c1,
                                              pbufPartial, dout);
    }
    tail_params<<<384, 256, 0, stream>>>(pbufPartial, bproj, dout, musig);
    gen_samples<<<6400, 256, 0, stream>>>(noise, musig, dout + (size_t)Bsz * Psteps * 2);
}

// Round 4
// 4068.372 us; speedup vs baseline: 1.4456x; 1.1508x over previous
//
#include <hip/hip_runtime.h>
#include <stdint.h>

#define Bsz 1024
#define Hsz 1024
#define Psteps 96
#define Ssamp 100
#define COVn 31

typedef __attribute__((ext_vector_type(8))) short short8;
typedef __attribute__((ext_vector_type(4))) float f32x4;

__device__ inline unsigned short f2bf(float f) {
    union { float f; unsigned u; } v; v.f = f;
    unsigned r = v.u + 0x7FFFu + ((v.u >> 16) & 1u);
    return (unsigned short)(r >> 16);
}

__device__ inline float sigm(float x) { return 1.f / (1.f + __expf(-x)); }
__device__ inline float tanh_f(float x) { return 2.f / (1.f + __expf(-2.f * x)) - 1.f; }
__device__ inline float softplusf(float x) {
    return fmaxf(x, 0.f) + log1pf(__expf(-fabsf(x)));
}

__device__ inline void gld16(const unsigned short* g, unsigned short* l) {
    auto gp = (const __attribute__((address_space(1))) unsigned int*)(const unsigned int*)g;
    auto lp = (__attribute__((address_space(3))) unsigned int*)(unsigned int*)l;
    __builtin_amdgcn_global_load_lds(gp, lp, 16, 0, 0);
}

// stage a ROWSx64 bf16 tile into LDS, source-side XOR-swizzled.
// chunk c at byte c*16; c = row*8 + s; content of (row,s) = global slot (s ^ (row&7)).
// CH = chunks per thread (ROWS*8/256).
template<int CH>
__device__ inline void stage_tile(const unsigned short* __restrict__ src, int rowStride,
                                  int row0, int k0, unsigned short* ldsBase, int tid) {
    #pragma unroll
    for (int i = 0; i < CH; ++i) {
        int c = i * 256 + tid;
        int row = c >> 3, s = c & 7;
        int col = ((s ^ (row & 7)) << 3) + k0;
        gld16(src + (size_t)(row0 + row) * rowStride + col, ldsBase + c * 8);
    }
}

// ---------------- prep kernels ----------------
// W0cat[4096][1088]: cols 0..31 = Wih0, 32..63 = 0, 64..1087 = Whh0 (gate rows interleaved g^=4h+g)
// W1cat[4096][2048]: cols 0..1023 = Wih1, 1024..2047 = Whh1
__global__ void prep_weights(const float* __restrict__ Wih0, const float* __restrict__ Whh0,
                             const float* __restrict__ Wih1, const float* __restrict__ Whh1,
                             const float* __restrict__ bih0, const float* __restrict__ bhh0,
                             const float* __restrict__ bih1, const float* __restrict__ bhh1,
                             unsigned short* __restrict__ W0cat, unsigned short* __restrict__ W1cat,
                             float* __restrict__ bias0, float* __restrict__ bias1) {
    const size_t N0 = (size_t)4096 * 1088;
    const size_t N1 = (size_t)4096 * 2048;
    const size_t total = N0 + N1 + 8192;
    for (size_t e = (size_t)blockIdx.x * 256 + threadIdx.x; e < total; e += (size_t)gridDim.x * 256) {
        if (e < N0) {
            int gh = (int)(e / 1088), col = (int)(e % 1088);
            int src = ((gh & 3) << 10) + (gh >> 2);
            float v;
            if (col < 32) v = Wih0[(size_t)src * 32 + col];
            else if (col < 64) v = 0.f;
            else v = Whh0[(size_t)src * 1024 + (col - 64)];
            W0cat[e] = f2bf(v);
        } else if (e < N0 + N1) {
            size_t m = e - N0;
            int gh = (int)(m >> 11), col = (int)(m & 2047);
            int src = ((gh & 3) << 10) + (gh >> 2);
            float v = (col < 1024) ? Wih1[(size_t)src * 1024 + col]
                                   : Whh1[(size_t)src * 1024 + (col - 1024)];
            W1cat[m] = f2bf(v);
        } else {
            size_t m = e - N0 - N1;             // 0..8191
            int which = (int)(m >> 12);
            int gh = (int)(m & 4095);
            int src = ((gh & 3) << 10) + (gh >> 2);
            if (which == 0) bias0[gh] = bih0[src] + bhh0[src];
            else            bias1[gh] = bih1[src] + bhh1[src];
        }
    }
}

__global__ void prep_state(const float* __restrict__ hinit, const float* __restrict__ cinit,
                           unsigned short* __restrict__ hb0, unsigned short* __restrict__ hb1,
                           float* __restrict__ c0, float* __restrict__ c1) {
    const size_t NM = (size_t)1024 * 1024;
    for (size_t e = (size_t)blockIdx.x * 256 + threadIdx.x; e < 4 * NM; e += (size_t)gridDim.x * 256) {
        if (e < NM) {
            hb0[e] = f2bf(hinit[e]);                       // h stored [B][H] bf16
        } else if (e < 2 * NM) {
            hb1[e - NM] = f2bf(hinit[e]);
        } else if (e < 3 * NM) {
            size_t j = e - 2 * NM; int h = (int)(j >> 10), b = (int)(j & 1023);
            c0[j] = cinit[(size_t)b * 1024 + h];           // c stored [H][B] f32
        } else {
            size_t j = e - 3 * NM; int h = (int)(j >> 10), b = (int)(j & 1023);
            c1[j] = cinit[NM + (size_t)b * 1024 + h];
        }
    }
}

// ---------------- LSTM step GEMM kernel ----------------
// gates^T = W_cat (M=4096, g^=4h+g interleaved) x input^T (N=1024 batch)
// tile 128(M)x64(N), BK=64, grid 32m x 16n = 512 blocks -> 2 blocks/CU.
// 4 waves as 2(M)x2(N); wave tile 64x32; acc[4][2].
// LDS 48KB: A dbuf 2x16KB @0/16K, B dbuf 2x8KB @32K/40K. Simple m97-style loop:
// stage(it+1) -> compute(it) -> __syncthreads(); co-resident block hides the drain.
template<int CELL>
__global__ __launch_bounds__(256, 2) void lstm_step(
        int t,
        const float* __restrict__ cov, const float* __restrict__ initv,
        const float* __restrict__ noise, const float* __restrict__ bproj,
        const float* __restrict__ wproj,
        const unsigned short* __restrict__ WA,   // W0cat or W1cat
        const float* __restrict__ biasH,
        const unsigned short* __restrict__ hA,   // cell1: h0_new (first K half)
        const unsigned short* __restrict__ hB,   // cell0: h0_prev; cell1: h1_prev
        unsigned short* __restrict__ hOut,
        float* __restrict__ cws,
        float* __restrict__ pbufPartial,         // [32 m][1024 b][2]
        float* __restrict__ outParams) {
    __shared__ __align__(16) char smem[49152];

    const int tid = threadIdx.x;
    const int m_tile = blockIdx.x & 31;          // xcd = blockIdx%8 = m_tile%8 -> A L2-resident
    const int n_tile = blockIdx.x >> 5;          // 0..15
    const int m0 = m_tile * 128;                 // gate-row base
    const int hc0 = m_tile * 32;                 // h base (128 gates / 4)
    const int b0 = n_tile * 64;
    const int lane = tid & 63;
    const int wid = tid >> 6;
    const int wm = wid >> 1, wn = wid & 1;
    const int NIT = (CELL == 0) ? 17 : 32;

    auto stageIt = [&](int j) {
        unsigned short* Ab = (unsigned short*)(smem + (j & 1) * 16384);
        unsigned short* Bb = (unsigned short*)(smem + 32768 + (j & 1) * 8192);
        if (CELL == 0) {
            stage_tile<4>(WA, 1088, m0, j * 64, Ab, tid);
            if (j > 0) stage_tile<2>(hB, 1024, b0, (j - 1) * 64, Bb, tid);
        } else {
            stage_tile<4>(WA, 2048, m0, j * 64, Ab, tid);
            if (j < 16) stage_tile<2>(hA, 1024, b0, j * 64, Bb, tid);
            else        stage_tile<2>(hB, 1024, b0, (j - 16) * 64, Bb, tid);
        }
    };

    // ---------- prologue: issue buf 0; build X (cell0) ----------
    stageIt(0);
    if (CELL == 0) {
        float* pj = (float*)(smem + 40960);           // B buf1 region (first staged at it=0 loop)
        float* curF = (float*)(smem + 40960 + 512);
        if (t > 0) {
            if (tid < 128) {
                int bl = tid >> 1, j = tid & 1;
                float s = bproj[j];
                #pragma unroll 8
                for (int m = 0; m < 32; ++m)
                    s += pbufPartial[(size_t)((m << 10) + b0 + bl) * 2 + j];
                pj[tid] = s;
                if (m_tile == 0)
                    outParams[((size_t)(b0 + bl) * Psteps + (t - 1)) * 2 + j] = s;
            }
        }
        __syncthreads();
        if (tid < 64) {
            float cu;
            if (t == 0) {
                cu = initv[b0 + tid];
            } else {
                float p0 = pj[tid * 2 + 0], p1 = pj[tid * 2 + 1];
                cu = p0 + (softplusf(p1) + 1e-6f) * noise[(size_t)(t - 1) * (Ssamp * Bsz) + b0 + tid];
            }
            curF[tid] = cu;
        }
        __syncthreads();
        // build X tile into B buffer 0 (64 rows x 64 cols, swizzled):
        // data cols 0..31 = [cur, cov0..30], cols 32..63 = 0
        #pragma unroll
        for (int i = 0; i < 2; ++i) {
            int c = i * 256 + tid;
            int row = c >> 3, s = c & 7;
            int ts = s ^ (row & 7);
            short8 v;
            if (ts < 4) {
                const float* cr = cov + ((size_t)(b0 + row) * Psteps + t) * COVn;
                #pragma unroll
                for (int e = 0; e < 8; ++e) {
                    int col = ts * 8 + e;
                    float x = (col == 0) ? curF[row] : cr[col - 1];
                    v[e] = (short)f2bf(x);
                }
            } else {
                v = (short8){0, 0, 0, 0, 0, 0, 0, 0};
            }
            *(short8*)(smem + 32768 + c * 16) = v;
        }
    }
    __syncthreads();   // buf 0 ready

    f32x4 acc[4][2];
    #pragma unroll
    for (int i = 0; i < 4; ++i)
        #pragma unroll
        for (int j = 0; j < 2; ++j) acc[i][j] = (f32x4){0.f, 0.f, 0.f, 0.f};

    // ---------- main loop ----------
    for (int it = 0; it < NIT; ++it) {
        if (it + 1 < NIT) stageIt(it + 1);
        const char* Abuf = smem + (it & 1) * 16384;
        const char* Bbuf = smem + 32768 + (it & 1) * 8192;
        __builtin_amdgcn_s_setprio(1);
        #pragma unroll
        for (int kh = 0; kh < 2; ++kh) {
            short8 af[4], bq[2];
            #pragma unroll
            for (int mf = 0; mf < 4; ++mf) {
                int row = wm * 64 + mf * 16 + (lane & 15);
                int slot = (kh * 4 + (lane >> 4)) ^ (row & 7);
                af[mf] = *(const short8*)(Abuf + row * 128 + slot * 16);
            }
            #pragma unroll
            for (int nf = 0; nf < 2; ++nf) {
                int row = wn * 32 + nf * 16 + (lane & 15);
                int slot = (kh * 4 + (lane >> 4)) ^ (row & 7);
                bq[nf] = *(const short8*)(Bbuf + row * 128 + slot * 16);
            }
            #pragma unroll
            for (int mf = 0; mf < 4; ++mf)
                #pragma unroll
                for (int nf = 0; nf < 2; ++nf)
                    acc[mf][nf] = __builtin_amdgcn_mfma_f32_16x16x32_bf16(af[mf], bq[nf], acc[mf][nf], 0, 0, 0);
        }
        __builtin_amdgcn_s_setprio(0);
        __syncthreads();
    }

    // ---------- epilogue ----------
    unsigned short* Ht = (unsigned short*)smem;      // [64 b][40] bf16
    float* part = (float*)(smem + 16384);            // [2 wm][64 b][2 j]
    float pp[2][2];
    if (CELL == 1) {
        #pragma unroll
        for (int nf = 0; nf < 2; ++nf) { pp[nf][0] = 0.f; pp[nf][1] = 0.f; }
    }
    #pragma unroll
    for (int mf = 0; mf < 4; ++mf) {
        int hl = wm * 16 + mf * 4 + (lane >> 4);
        int h = hc0 + hl;
        f32x4 bs = *(const f32x4*)&biasH[h * 4];
        #pragma unroll
        for (int nf = 0; nf < 2; ++nf) {
            int bl = wn * 32 + nf * 16 + (lane & 15);
            int b = b0 + bl;
            f32x4 v = acc[mf][nf];
            float gi = sigm(v.x + bs.x);
            float gf = sigm(v.y + bs.y);
            float gg = tanh_f(v.z + bs.z);
            float go = sigm(v.w + bs.w);
            size_t ci = (size_t)h * Bsz + b;
            float cn = gf * cws[ci] + gi * gg;
            cws[ci] = cn;
            float hn = go * tanh_f(cn);
            Ht[bl * 40 + hl] = f2bf(hn);
            if (CELL == 1) {
                pp[nf][0] += hn * wproj[h];
                pp[nf][1] += hn * wproj[Hsz + h];
            }
        }
    }
    if (CELL == 1) {
        #pragma unroll
        for (int nf = 0; nf < 2; ++nf)
            #pragma unroll
            for (int j = 0; j < 2; ++j) {
                float v = pp[nf][j];
                v += __shfl_xor(v, 16, 64);
                v += __shfl_xor(v, 32, 64);
                if (lane < 16)
                    part[((wm * 64) + wn * 32 + nf * 16 + lane) * 2 + j] = v;
            }
    }
    __syncthreads();
    if (tid < 128) {   // coalesced h write: 64 rows x 64B contiguous
        int row = tid >> 1, hf = tid & 1;
        short8 v0 = *(const short8*)&Ht[row * 40 + hf * 16];
        short8 v1 = *(const short8*)&Ht[row * 40 + hf * 16 + 8];
        *(short8*)&hOut[(size_t)(b0 + row) * Hsz + hc0 + hf * 16] = v0;
        *(short8*)&hOut[(size_t)(b0 + row) * Hsz + hc0 + hf * 16 + 8] = v1;
    }
    if (CELL == 1 && tid < 128) {
        int bl = tid >> 1, j = tid & 1;
        pbufPartial[((size_t)m_tile * 1024 + b0 + bl) * 2 + j] =
            part[bl * 2 + j] + part[(64 + bl) * 2 + j];
    }
}

// ---------------- tail: params[t=95] + mu/sigma table ----------------
__global__ void tail_params(const float* __restrict__ pPart, const float* __restrict__ bproj,
                            float* __restrict__ dout, float* __restrict__ musig) {
    int idx = blockIdx.x * 256 + threadIdx.x;
    if (idx >= Bsz * Psteps) return;
    int b = idx / Psteps, t = idx % Psteps;
    float p0, p1;
    if (t == Psteps - 1) {
        p0 = bproj[0]; p1 = bproj[1];
        #pragma unroll 8
        for (int m = 0; m < 32; ++m) {
            p0 += pPart[(size_t)((m << 10) + b) * 2 + 0];
            p1 += pPart[(size_t)((m << 10) + b) * 2 + 1];
        }
        dout[(size_t)idx * 2 + 0] = p0;
        dout[(size_t)idx * 2 + 1] = p1;
    } else {
        p0 = dout[(size_t)idx * 2 + 0];
        p1 = dout[(size_t)idx * 2 + 1];
    }
    musig[(size_t)idx * 2 + 0] = p0;
    musig[(size_t)idx * 2 + 1] = softplusf(p1) + 1e-6f;
}

// ---------------- sample generation (out layout (S,B,P)) ----------------
// grid = 100 s * 64 batch-chunks = 6400 blocks of (s, 16 batch)
__global__ __launch_bounds__(256) void gen_samples(const float* __restrict__ noise,
                                                   const float* __restrict__ musig,
                                                   float* __restrict__ outS) {
    __shared__ float tile[16][97];
    int s = blockIdx.x >> 6;
    int b0 = (blockIdx.x & 63) << 4;
    int tid = threadIdx.x;
    for (int e = tid; e < Psteps * 16; e += 256) {
        int tt = e >> 4, b = e & 15;
        tile[b][tt] = noise[((size_t)tt * Ssamp + s) * Bsz + b0 + b];
    }
    __syncthreads();
    int b = tid >> 4, t0 = (tid & 15) * 6;
    const float* ms = musig + ((size_t)(b0 + b) * Psteps + t0) * 2;
    float* op = outS + ((size_t)s * Bsz + b0 + b) * Psteps + t0;
    #pragma unroll
    for (int k = 0; k < 6; ++k) {
        op[k] = ms[k * 2] + ms[k * 2 + 1] * tile[b][t0 + k];
    }
}

// ---------------- host ----------------
extern "C" void kernel_launch(void* const* d_in, const int* in_sizes, int n_in,
                              void* d_out, int out_size, void* d_ws, size_t ws_size,
                              hipStream_t stream) {
    const float* cov   = (const float*)d_in[0];
    const float* initv = (const float*)d_in[1];
    const float* noise = (const float*)d_in[2];
    const float* hinit = (const float*)d_in[3];
    const float* cinit = (const float*)d_in[4];
    const float* Wih0  = (const float*)d_in[5];
    const float* Whh0  = (const float*)d_in[6];
    const float* bih0  = (const float*)d_in[7];
    const float* bhh0  = (const float*)d_in[8];
    const float* Wih1  = (const float*)d_in[9];
    const float* Whh1  = (const float*)d_in[10];
    const float* bih1  = (const float*)d_in[11];
    const float* bih1x = bih1;
    const float* bhh1  = (const float*)d_in[12];
    const float* wproj = (const float*)d_in[13];
    const float* bproj = (const float*)d_in[14];
    (void)bih1x;
    float* dout = (float*)d_out;

    uint8_t* p = (uint8_t*)d_ws;
    auto alloc = [&](size_t bytes) { void* r = (void*)p; p += (bytes + 255) & ~(size_t)255; return r; };
    unsigned short* W0cat = (unsigned short*)alloc((size_t)4096 * 1088 * 2);
    unsigned short* W1cat = (unsigned short*)alloc((size_t)4096 * 2048 * 2);
    float* bias0 = (float*)alloc(4096 * 4);
    float* bias1 = (float*)alloc(4096 * 4);
    unsigned short* hb0 = (unsigned short*)alloc((size_t)2 * 1024 * 1024 * 2 + 256);
    unsigned short* hb1 = (unsigned short*)alloc((size_t)2 * 1024 * 1024 * 2 + 256);
    float* c0 = (float*)alloc((size_t)1024 * 1024 * 4);
    float* c1 = (float*)alloc((size_t)1024 * 1024 * 4);
    float* pbufPartial = (float*)alloc((size_t)32 * 1024 * 2 * 4);
    float* musig = (float*)alloc((size_t)1024 * 96 * 2 * 4);

    prep_weights<<<2048, 256, 0, stream>>>(Wih0, Whh0, Wih1, Whh1, bih0, bhh0, bih1, bhh1,
                                           W0cat, W1cat, bias0, bias1);
    prep_state<<<2048, 256, 0, stream>>>(hinit, cinit, hb0, hb1, c0, c1);

    const size_t HB = (size_t)1024 * 1024;
    for (int t = 0; t < Psteps; ++t) {
        const unsigned short* h0p = hb0 + (size_t)(t & 1) * HB;
        unsigned short* h0n = hb0 + (size_t)((t + 1) & 1) * HB;
        const unsigned short* h1p = hb1 + (size_t)(t & 1) * HB;
        unsigned short* h1n = hb1 + (size_t)((t + 1) & 1) * HB;
        lstm_step<0><<<512, 256, 0, stream>>>(t, cov, initv, noise, bproj, wproj,
                                              W0cat, bias0, nullptr, h0p, h0n, c0,
                                              pbufPartial, dout);
        lstm_step<1><<<512, 256, 0, stream>>>(t, cov, initv, noise, bproj, wproj,
                                              W1cat, bias1, h0n, h1p, h1n, c1,
                                              pbufPartial, dout);
    }
    tail_params<<<384, 256, 0, stream>>>(pbufPartial, bproj, dout, musig);
    gen_samples<<<6400, 256, 0, stream>>>(noise, musig, dout + (size_t)Bsz * Psteps * 2);
}